// Round 5
// baseline (1252.939 us; speedup 1.0000x reference)
//
#include <hip/hip_runtime.h>
#include <hip/hip_bf16.h>

#define NN 10000
#define NE 50000

typedef __attribute__((ext_vector_type(8))) short bfrag8;  // 8 bf16 = 4 VGPR (MFMA A/B)
typedef __attribute__((ext_vector_type(4))) short s16x4;   // 4 bf16 = b64 store
typedef __attribute__((ext_vector_type(4))) float f32x4;   // MFMA C/D

__device__ __forceinline__ float silu_f(float v){ return v / (1.0f + __expf(-v)); }
__device__ __forceinline__ short f2b(float f){           // f32 -> bf16 RNE
  unsigned u = __float_as_uint(f);
  u += 0x7fffu + ((u>>16)&1u);
  return (short)(u>>16);
}
__device__ __forceinline__ float b2f(short s){
  return __uint_as_float(((unsigned)(unsigned short)s)<<16);
}

// ------- K0: hT[n][c][32] = rmsnorm(x,g1) transposed, j-padded, bf16 -------
__global__ __launch_bounds__(256) void k_rms1T(const float* __restrict__ x,
                                               const float* __restrict__ gamma,
                                               short* __restrict__ hT){
  int idx = blockIdx.x*256 + threadIdx.x;
  if (idx >= NN*64) return;
  int n = idx>>6, c = idx&63;
  const float* xp = x + (size_t)n*1600 + c;
  float ss = 0.f;
#pragma unroll
  for (int i=0;i<25;i++){ float v = xp[i*64]; ss += v*v; }
  float inv = gamma[c] * rsqrtf(ss*(1.f/25.f) + 1e-6f);
  short buf[32];
#pragma unroll
  for (int i=0;i<25;i++) buf[i] = f2b(xp[i*64]*inv);
#pragma unroll
  for (int i=25;i<32;i++) buf[i] = 0;
  short* hp = hT + (size_t)n*2048 + c*32;
#pragma unroll
  for (int k=0;k<8;k++){
    s16x4 o; o[0]=buf[k*4]; o[1]=buf[k*4+1]; o[2]=buf[k*4+2]; o[3]=buf[k*4+3];
    *(s16x4*)&hp[k*4] = o;
  }
}

// ------------- Kprep: weights -> MFMA bf16 / f32 layouts -------------
__global__ void k_wprep(const float* __restrict__ W1, const float* __restrict__ tog,
                        const float* __restrict__ fromg, const float* __restrict__ proj,
                        const float* __restrict__ fw1, const float* __restrict__ fw2,
                        const float* __restrict__ rw1, const float* __restrict__ rw2,
                        const float* __restrict__ rw3, const float* __restrict__ w0e,
                        short* __restrict__ w1t, short* __restrict__ togA,
                        short* __restrict__ fgA, short* __restrict__ projT,
                        short* __restrict__ fw1T, short* __restrict__ fw2T,
                        short* __restrict__ rw1T, short* __restrict__ rw2T,
                        short* __restrict__ rw3T, float* __restrict__ w0eN){
  int t0 = blockIdx.x*blockDim.x + threadIdx.x;
  int stride = gridDim.x*blockDim.x;
  for (int idx=t0; idx<64*136; idx+=stride){
    int hh = idx/136, k = idx-136*hh;
    w1t[idx] = (k<128) ? f2b(W1[k*64+hh]) : (short)0;
  }
  for (int idx=t0; idx<48*40; idx+=stride){
    int g = idx/40, i = idx-40*g;
    togA[idx] = (g<36 && i<25) ? f2b(tog[g*25+i]) : (short)0;
  }
  for (int idx=t0; idx<32*72; idx+=stride){
    int j = idx/72, g = idx-72*j;
    fgA[idx] = (j<25 && g<36) ? f2b(fromg[j*36+g]) : (short)0;
  }
  for (int idx=t0; idx<64*64; idx+=stride){   // projT[c][k] = proj[k][c]
    int c = idx>>6, k = idx&63;
    projT[idx] = f2b(proj[k*64+c]);
  }
  for (int idx=t0; idx<128*64; idx+=stride){  // fw1T[f][c] = fw1[c][f]
    int f = idx>>6, c = idx&63;
    fw1T[idx] = f2b(fw1[c*128+f]);
  }
  for (int idx=t0; idx<64*128; idx+=stride){  // fw2T[c][f] = fw2[f][c]
    int c = idx>>7, f = idx&127;
    fw2T[idx] = f2b(fw2[f*64+c]);
  }
  for (int idx=t0; idx<64*96; idx+=stride){   // rw1T[n][k] = rw1[k][n]
    int n = idx/96, k = idx-96*n;
    rw1T[idx] = f2b(rw1[k*64+n]);
  }
  for (int idx=t0; idx<64*64; idx+=stride){   // rw2T[n][k] = rw2[k][n]
    int n = idx>>6, k = idx&63;
    rw2T[idx] = f2b(rw2[k*64+n]);
  }
  for (int idx=t0; idx<640*64; idx+=stride){  // rw3T[n][k] = rw3[k][n]
    int n = idx>>6, k = idx&63;
    rw3T[idx] = f2b(rw3[(size_t)k*640+n]);
  }
  for (int idx=t0; idx<192*128; idx+=stride){ // w0eN[n][c] = w0e[c][n], f32
    int n = idx>>7, c = idx&127;
    w0eN[idx] = w0e[c*192+n];
  }
}

// ---------------- K1: radial MLP, MFMA, 32 edges/block ----------------
__global__ __launch_bounds__(256,4) void k_radial(
  const int* __restrict__ ei, const int* __restrict__ an,
  const float* __restrict__ edist,
  const float* __restrict__ stab, const float* __restrict__ ttab,
  const short* __restrict__ rw1T, const float* __restrict__ rb1,
  const short* __restrict__ rw2T, const float* __restrict__ rb2,
  const short* __restrict__ rw3T, const float* __restrict__ rb3,
  short* __restrict__ rfS)
{
  __shared__ __align__(16) short SP[7936];
  const int tid = threadIdx.x;
  const int wv = tid>>6, lane = tid&63, lo = lane&15, q = lane>>4;
  const int e0 = blockIdx.x*32;
  {
    int e = tid>>3;
    int ee = min(e0+e, NE-1);
    int srcE = ei[ee], dstE = ei[NE+ee];
    const float* dp = edist + (size_t)ee*32;
    const float* sp = stab + (size_t)an[srcE]*32;
    const float* tp = ttab + (size_t)an[dstE]*32;
    int kb = tid&7;
#pragma unroll
    for (int it=0; it<12; ++it){
      int k = kb + it*8;
      float v = (k<32) ? dp[k] : (k<64 ? sp[k-32] : tp[k-64]);
      SP[e*104+k] = f2b(v);
    }
  }
  __syncthreads();
  { // r1
    f32x4 zf={0.f,0.f,0.f,0.f}; f32x4 acc[2]={zf,zf};
#pragma unroll
    for (int kt=0;kt<3;kt++){
      bfrag8 a = *(const bfrag8*)&rw1T[(wv*16+lo)*96 + kt*32 + q*8];
#pragma unroll
      for (int et=0;et<2;et++){
        bfrag8 b = *(const bfrag8*)&SP[(et*16+lo)*104 + kt*32 + q*8];
        acc[et] = __builtin_amdgcn_mfma_f32_16x16x32_bf16(a,b,acc[et],0,0,0);
      }
    }
    int n1 = wv*16 + q*4;
    const float4 bb = *(const float4*)&rb1[n1];
#pragma unroll
    for (int et=0;et<2;et++){
      s16x4 o;
      o[0]=f2b(silu_f(acc[et][0]+bb.x)); o[1]=f2b(silu_f(acc[et][1]+bb.y));
      o[2]=f2b(silu_f(acc[et][2]+bb.z)); o[3]=f2b(silu_f(acc[et][3]+bb.w));
      *(s16x4*)&SP[3328 + (et*16+lo)*72 + n1] = o;
    }
  }
  __syncthreads();
  { // r2
    f32x4 zf={0.f,0.f,0.f,0.f}; f32x4 acc[2]={zf,zf};
#pragma unroll
    for (int kt=0;kt<2;kt++){
      bfrag8 a = *(const bfrag8*)&rw2T[(wv*16+lo)*64 + kt*32 + q*8];
#pragma unroll
      for (int et=0;et<2;et++){
        bfrag8 b = *(const bfrag8*)&SP[3328 + (et*16+lo)*72 + kt*32 + q*8];
        acc[et] = __builtin_amdgcn_mfma_f32_16x16x32_bf16(a,b,acc[et],0,0,0);
      }
    }
    int n2 = wv*16 + q*4;
    const float4 bb = *(const float4*)&rb2[n2];
#pragma unroll
    for (int et=0;et<2;et++){
      s16x4 o;
      o[0]=f2b(silu_f(acc[et][0]+bb.x)); o[1]=f2b(silu_f(acc[et][1]+bb.y));
      o[2]=f2b(silu_f(acc[et][2]+bb.z)); o[3]=f2b(silu_f(acc[et][3]+bb.w));
      *(s16x4*)&SP[5632 + (et*16+lo)*72 + n2] = o;
    }
  }
  __syncthreads();
  { // r3 -> rfS
    bfrag8 bfr[2][2];
#pragma unroll
    for (int et=0;et<2;et++)
#pragma unroll
      for (int kt=0;kt<2;kt++)
        bfr[et][kt] = *(const bfrag8*)&SP[5632 + (et*16+lo)*72 + kt*32 + q*8];
    for (int mi=0; mi<10; ++mi){
      int n3base = (wv + mi*4)*16;
      f32x4 zf={0.f,0.f,0.f,0.f}; f32x4 acc[2]={zf,zf};
#pragma unroll
      for (int kt=0;kt<2;kt++){
        bfrag8 a = *(const bfrag8*)&rw3T[(size_t)(n3base+lo)*64 + kt*32 + q*8];
        acc[0] = __builtin_amdgcn_mfma_f32_16x16x32_bf16(a,bfr[0][kt],acc[0],0,0,0);
        acc[1] = __builtin_amdgcn_mfma_f32_16x16x32_bf16(a,bfr[1][kt],acc[1],0,0,0);
      }
      int n3 = n3base + q*4;
      const float4 bb = *(const float4*)&rb3[n3];
#pragma unroll
      for (int et=0;et<2;et++){
        int e = e0 + et*16 + lo;
        if (e < NE){
          s16x4 o;
          o[0]=f2b(acc[et][0]+bb.x); o[1]=f2b(acc[et][1]+bb.y);
          o[2]=f2b(acc[et][2]+bb.z); o[3]=f2b(acc[et][3]+bb.w);
          *(s16x4*)&rfS[(size_t)e*640 + n3] = o;
        }
      }
    }
  }
}

// ---------------- K3: MFMA edge kernel + fused alpha/gate ----------------
// POOL (shorts): sgB@0[64][72]=4608  wA@4608[32][40]  wT@5888[32][40]
//   xeB@7168[32][136] (aliased by msgs2B[64][40])  msgsB@11520[64][40]
//   rfull(f32)@14080[640]  gateL(f32)@15360[128sh]  ahead(f32)@15488[16sh]
//   exL(f32)@15504[256sh]  xe0F(f32)@15760[256sh]  -> 16016 sh = 32032 B
__global__ __launch_bounds__(256,4) void k_edge(
  const short* __restrict__ hT, const int* __restrict__ ei,
  const float* __restrict__ wig,
  const short* __restrict__ w1t, const short* __restrict__ togA,
  const short* __restrict__ fgA, const float* __restrict__ w0eN,
  const float* __restrict__ adot,
  const short* __restrict__ rfS, float* __restrict__ asum,
  float* __restrict__ agg)
{
  __shared__ __align__(16) short POOL[16016];
  float* rfull = (float*)&POOL[14080];
  float* gateL = (float*)&POOL[15360];
  float* ahead = (float*)&POOL[15488];
  float* exL   = (float*)&POOL[15504];
  float* xe0F  = (float*)&POOL[15760];
  const int tid = threadIdx.x;
  const int wv = tid>>6, lane = tid&63, lo = lane&15, q = lane>>4;
  const int e = blockIdx.x;
  const int src = ei[e], dst = ei[NE+e];
  const short* hbase = hT + (size_t)(wv<2 ? src : dst)*2048;

  { // zero sgB+wA+wT ([0,7168) shorts = 896 int4): K-padding + NaN safety
    int4 z; z.x=0; z.y=0; z.z=0; z.w=0;
    int4* zp = (int4*)POOL;
    for (int idx=tid; idx<896; idx+=256) zp[idx] = z;
  }
  __syncthreads();
  // stage wigner -> wA[i][j], wT[j->i transposed]
  for (int idx=tid; idx<625; idx+=256){
    int i = idx/25, j = idx-25*i;
    short v = f2b(wig[(size_t)e*625+idx]);
    POOL[4608 + i*40 + j] = v;
    POOL[5888 + j*40 + i] = v;
  }
  for (int idx=tid; idx<640; idx+=256) rfull[idx] = b2f(rfS[(size_t)e*640+idx]);
  __syncthreads();

  { // rot1: xe[i][c] = sum_j W[i][j] h[j][c], *r.  M=c(128) N=i(32) K=j(32)
    // A = hT rows (global, issued at kernel start), B = wA (LDS)
    f32x4 zf = {0.f,0.f,0.f,0.f};
    f32x4 acc[2][2] = {{zf,zf},{zf,zf}};
    bfrag8 b0 = *(const bfrag8*)&POOL[4608 + (lo)*40 + q*8];
    bfrag8 b1 = *(const bfrag8*)&POOL[4608 + (16+lo)*40 + q*8];
#pragma unroll
    for (int t=0;t<2;t++){
      int crow = ((2*wv+t)*16 + lo) & 63;
      bfrag8 a = *(const bfrag8*)&hbase[crow*32 + q*8];
      acc[t][0] = __builtin_amdgcn_mfma_f32_16x16x32_bf16(a, b0, acc[t][0], 0,0,0);
      acc[t][1] = __builtin_amdgcn_mfma_f32_16x16x32_bf16(a, b1, acc[t][1], 0,0,0);
    }
#pragma unroll
    for (int t=0;t<2;t++){
      int c0 = (2*wv+t)*16 + q*4;
#pragma unroll
      for (int nt=0;nt<2;nt++){
        int i = nt*16 + lo;
        int l = (i>=16)?4:((i>=9)?3:((i>=4)?2:((i>=1)?1:0)));
        const f32x4 rv = *(const f32x4*)&rfull[l*128 + c0];
        f32x4 p;
#pragma unroll
        for (int r=0;r<4;r++) p[r] = acc[t][nt][r]*rv[r];
        s16x4 o;
#pragma unroll
        for (int r=0;r<4;r++) o[r] = f2b(p[r]);
        *(s16x4*)&POOL[7168 + i*136 + c0] = o;
        if (nt==0 && lo==0){           // row i==0: keep f32 xe0r for alpha/gate
          float4 pf; pf.x=p[0]; pf.y=p[1]; pf.z=p[2]; pf.w=p[3];
          *(float4*)&xe0F[c0] = pf;
        }
      }
    }
  }
  __syncthreads();

  if (tid < 192){ // extra = xe0r @ W0_extra (f32, vectorized, one n per thread)
    float s = 0.f;
    const float* wrow = w0eN + (size_t)tid*128;
#pragma unroll 8
    for (int kt=0; kt<32; ++kt){
      const float4 xv = *(const float4*)&xe0F[kt*4];
      const float4 wv4 = *(const float4*)&wrow[kt*4];
      s += xv.x*wv4.x + xv.y*wv4.y + xv.z*wv4.z + xv.w*wv4.w;
    }
    if (tid < 128) exL[tid] = silu_f(s)*adot[tid];
    else           gateL[tid-128] = silu_f(s);
  }
  { // msg: msgs[i][h] = sum_c xe[i][c] W1[c][h]
    const int hh = wv*16 + lo;
    f32x4 zf = {0.f,0.f,0.f,0.f};
    f32x4 acc[2] = {zf,zf};
#pragma unroll
    for (int kt=0;kt<4;kt++){
      bfrag8 b = *(const bfrag8*)&w1t[hh*136 + kt*32 + q*8];
#pragma unroll
      for (int t=0;t<2;t++){
        bfrag8 a = *(const bfrag8*)&POOL[7168 + (t*16+lo)*136 + kt*32 + q*8];
        acc[t] = __builtin_amdgcn_mfma_f32_16x16x32_bf16(a, b, acc[t], 0,0,0);
      }
    }
#pragma unroll
    for (int t=0;t<2;t++){
      s16x4 o;
#pragma unroll
      for (int r=0;r<4;r++) o[r] = f2b(acc[t][r]);
      *(s16x4*)&POOL[11520 + hh*40 + t*16 + q*4] = o;
    }
  }
  __syncthreads();

  if (tid < 8){ // alpha head-reduce + exp (UNNORMALIZED; k_node divides)
    float s = 0.f;
#pragma unroll
    for (int a=0;a<16;a++) s += exL[tid*16+a];
    float eh = __expf(s);
    ahead[tid] = eh;
    unsafeAtomicAdd(&asum[(size_t)dst*8 + tid], eh);
  }
  { // grid fwd
    const int hh = wv*16 + lo;
    bfrag8 b = *(const bfrag8*)&POOL[11520 + hh*40 + q*8];
    f32x4 zf = {0.f,0.f,0.f,0.f};
    f32x4 acc[3] = {zf,zf,zf};
#pragma unroll
    for (int t=0;t<3;t++){
      bfrag8 a = *(const bfrag8*)&togA[(t*16+lo)*40 + q*8];
      acc[t] = __builtin_amdgcn_mfma_f32_16x16x32_bf16(a, b, acc[t], 0,0,0);
    }
#pragma unroll
    for (int t=0;t<3;t++){
      s16x4 o;
#pragma unroll
      for (int r=0;r<4;r++) o[r] = f2b(silu_f(acc[t][r]));
      *(s16x4*)&POOL[hh*72 + t*16 + q*4] = o;
    }
  }
  __syncthreads();

  { // grid bwd; row0<-gate; * exp(alpha) per head
    const int hh = wv*16 + lo;
    f32x4 zf = {0.f,0.f,0.f,0.f};
    f32x4 acc[2] = {zf,zf};
#pragma unroll
    for (int kt=0;kt<2;kt++){
      bfrag8 b = *(const bfrag8*)&POOL[hh*72 + kt*32 + q*8];
#pragma unroll
      for (int t=0;t<2;t++){
        bfrag8 a = *(const bfrag8*)&fgA[(t*16+lo)*72 + kt*32 + q*8];
        acc[t] = __builtin_amdgcn_mfma_f32_16x16x32_bf16(a, b, acc[t], 0,0,0);
      }
    }
    float ah = ahead[hh>>3];
#pragma unroll
    for (int t=0;t<2;t++){
      s16x4 o;
#pragma unroll
      for (int r=0;r<4;r++){
        int j = t*16 + q*4 + r;
        float v = acc[t][r];
        if (j==0) v = gateL[hh];
        o[r] = f2b(v*ah);
      }
      *(s16x4*)&POOL[7168 + hh*40 + t*16 + q*4] = o;
    }
  }
  __syncthreads();

  { // rot2 + scatter
    const int hh = wv*16 + lo;
    bfrag8 b = *(const bfrag8*)&POOL[7168 + hh*40 + q*8];
    f32x4 zf = {0.f,0.f,0.f,0.f};
    f32x4 acc[2] = {zf,zf};
#pragma unroll
    for (int t=0;t<2;t++){
      bfrag8 a = *(const bfrag8*)&POOL[5888 + (t*16+lo)*40 + q*8];
      acc[t] = __builtin_amdgcn_mfma_f32_16x16x32_bf16(a, b, acc[t], 0,0,0);
    }
    float* aggp = agg + (size_t)dst*1600;
#pragma unroll
    for (int t=0;t<2;t++){
#pragma unroll
      for (int r=0;r<4;r++){
        int i = t*16 + q*4 + r;
        if (i<25) unsafeAtomicAdd(&aggp[i*64+hh], acc[t][r]);
      }
    }
  }
}

// ---------------- K4: node update + FFN, MFMA ----------------
__global__ __launch_bounds__(256,4) void k_node(
  const float* __restrict__ x, const float* __restrict__ aggin,
  const float* __restrict__ asum,
  const short* __restrict__ projT, const float* __restrict__ gamma2,
  const float* __restrict__ glw, const float* __restrict__ glb,
  const short* __restrict__ fw1T, const float* __restrict__ fb1,
  const short* __restrict__ fw2T, const float* __restrict__ fb2,
  const short* __restrict__ togA, const short* __restrict__ fgA,
  float* __restrict__ out)
{
  __shared__ __align__(16) short P[19072];
  float* xF    = (float*)P;
  short* sgB   = P + 4352;
  short* hh2B  = P + 4352;
  short* f1B   = P + 13568;
  short* aggB  = P + 13568;
  short* xgB   = P + 13568;
  float* invc  = ((float*)P) + 9344;
  float* gateF = ((float*)P) + 9408;
  const int tid = threadIdx.x;
  const int wv = tid>>6, lane = tid&63, lo = lane&15, q = lane>>4;
  const int n = blockIdx.x;
  const s16x4 z4 = {0,0,0,0};

  for (int idx=tid; idx<400; idx+=256){
    int i = idx>>4, k = idx&15;
    float sc = 1.f/(asum[(size_t)n*8 + (k>>1)] + 1e-8f);
    const float4 v = *(const float4*)(aggin + (size_t)n*1600 + (size_t)idx*4);
    s16x4 o; o[0]=f2b(v.x*sc); o[1]=f2b(v.y*sc); o[2]=f2b(v.z*sc); o[3]=f2b(v.w*sc);
    *(s16x4*)&aggB[i*72 + k*4] = o;
  }
  for (int idx=tid; idx<126; idx+=256)
    *(s16x4*)&hh2B[25*72 + idx*4] = z4;
  for (int idx=tid; idx<512; idx+=256){
    int f = idx>>2, gg = 48 + (idx&3)*4;
    *(s16x4*)&sgB[f*72 + gg] = z4;
  }
  __syncthreads();

  { // xnew = x + (agg/denom)@proj
    f32x4 zf={0.f,0.f,0.f,0.f}; f32x4 acc[2]={zf,zf};
    const int c = wv*16 + lo;
#pragma unroll
    for (int kt=0;kt<2;kt++){
      bfrag8 b = *(const bfrag8*)&projT[c*64 + kt*32 + q*8];
#pragma unroll
      for (int t=0;t<2;t++){
        bfrag8 a = *(const bfrag8*)&aggB[(t*16+lo)*72 + kt*32 + q*8];
        acc[t] = __builtin_amdgcn_mfma_f32_16x16x32_bf16(a,b,acc[t],0,0,0);
      }
    }
#pragma unroll
    for (int t=0;t<2;t++)
#pragma unroll
      for (int r=0;r<4;r++){
        int i = t*16 + q*4 + r;
        if (i<25) xF[i*68+c] = acc[t][r] + x[(size_t)n*1600 + i*64 + c];
      }
  }
  __syncthreads();
  if (tid<64){
    float ss=0.f;
#pragma unroll
    for (int i=0;i<25;i++){ float v = xF[i*68+tid]; ss += v*v; }
    invc[tid] = gamma2[tid]*rsqrtf(ss*(1.f/25.f)+1e-6f);
  }
  __syncthreads();
  for (int idx=tid; idx<1600; idx+=256){
    int i=idx>>6, c=idx&63;
    hh2B[i*72+c] = f2b(xF[i*68+c]*invc[c]);
  }
  if (tid<128){
    float a = glb[tid];
#pragma unroll 8
    for (int c=0;c<64;c++) a += xF[c]*invc[c]*glw[c*128+tid];
    gateF[tid] = silu_f(a);
  }
  __syncthreads();

  { // f1 = hh2 @ fw1 -> f1B[f][i]
    f32x4 zf={0.f,0.f,0.f,0.f}; f32x4 acc[2][2]={{zf,zf},{zf,zf}};
#pragma unroll
    for (int kt=0;kt<2;kt++){
      bfrag8 a0 = *(const bfrag8*)&hh2B[(lo)*72 + kt*32 + q*8];
      bfrag8 a1 = *(const bfrag8*)&hh2B[(16+lo)*72 + kt*32 + q*8];
#pragma unroll
      for (int s=0;s<2;s++){
        int f = wv*32 + s*16 + lo;
        bfrag8 b = *(const bfrag8*)&fw1T[f*64 + kt*32 + q*8];
        acc[0][s] = __builtin_amdgcn_mfma_f32_16x16x32_bf16(a0,b,acc[0][s],0,0,0);
        acc[1][s] = __builtin_amdgcn_mfma_f32_16x16x32_bf16(a1,b,acc[1][s],0,0,0);
      }
    }
#pragma unroll
    for (int s=0;s<2;s++){
      int f = wv*32 + s*16 + lo;
      float bb = fb1[f];
#pragma unroll
      for (int t=0;t<2;t++){
        s16x4 o;
#pragma unroll
        for (int r=0;r<4;r++){
          int i = t*16+q*4+r;
          o[r] = f2b(acc[t][s][r] + (i==0 ? bb : 0.f));
        }
        *(s16x4*)&f1B[f*40 + t*16 + q*4] = o;
      }
    }
  }
  __syncthreads();

  { // sg = silu(tog @ f1) -> sgB[f][g]
    f32x4 zf={0.f,0.f,0.f,0.f}; f32x4 acc[3][2]={{zf,zf},{zf,zf},{zf,zf}};
    bfrag8 a0 = *(const bfrag8*)&togA[(lo)*40 + q*8];
    bfrag8 a1 = *(const bfrag8*)&togA[(16+lo)*40 + q*8];
    bfrag8 a2 = *(const bfrag8*)&togA[(32+lo)*40 + q*8];
#pragma unroll
    for (int s=0;s<2;s++){
      int f = wv*32 + s*16 + lo;
      bfrag8 b = *(const bfrag8*)&f1B[f*40 + q*8];
      acc[0][s] = __builtin_amdgcn_mfma_f32_16x16x32_bf16(a0,b,acc[0][s],0,0,0);
      acc[1][s] = __builtin_amdgcn_mfma_f32_16x16x32_bf16(a1,b,acc[1][s],0,0,0);
      acc[2][s] = __builtin_amdgcn_mfma_f32_16x16x32_bf16(a2,b,acc[2][s],0,0,0);
    }
#pragma unroll
    for (int s=0;s<2;s++){
      int f = wv*32 + s*16 + lo;
#pragma unroll
      for (int t=0;t<3;t++){
        s16x4 o;
#pragma unroll
        for (int r=0;r<4;r++) o[r] = f2b(silu_f(acc[t][s][r]));
        *(s16x4*)&sgB[f*72 + t*16 + q*4] = o;
      }
    }
  }
  __syncthreads();

  { // transposed grid bwd -> xgB[j][f] (+gate row j==0)
    f32x4 zf={0.f,0.f,0.f,0.f}; f32x4 acc[2][2]={{zf,zf},{zf,zf}};
#pragma unroll
    for (int kt=0;kt<2;kt++){
#pragma unroll
      for (int t=0;t<2;t++){
        bfrag8 b = *(const bfrag8*)&fgA[(t*16+lo)*72 + kt*32 + q*8];
#pragma unroll
        for (int s=0;s<2;s++){
          bfrag8 a = *(const bfrag8*)&sgB[(wv*32+s*16+lo)*72 + kt*32 + q*8];
          acc[s][t] = __builtin_amdgcn_mfma_f32_16x16x32_bf16(a,b,acc[s][t],0,0,0);
        }
      }
    }
#pragma unroll
    for (int s=0;s<2;s++){
      int f0 = wv*32 + s*16 + q*4;
#pragma unroll
      for (int t=0;t<2;t++){
        int j = t*16 + lo;
        s16x4 o;
#pragma unroll
        for (int r=0;r<4;r++)
          o[r] = f2b(j==0 ? gateF[f0+r] : acc[s][t][r]);
        *(s16x4*)&xgB[j*136 + f0] = o;
      }
    }
  }
  __syncthreads();

  { // f2 = xg @ fw2; out = xnew + f2 (+fb2 row0)
    f32x4 zf={0.f,0.f,0.f,0.f}; f32x4 acc[2]={zf,zf};
    const int c = wv*16 + lo;
#pragma unroll
    for (int kt=0;kt<4;kt++){
      bfrag8 b = *(const bfrag8*)&fw2T[c*128 + kt*32 + q*8];
#pragma unroll
      for (int t=0;t<2;t++){
        bfrag8 a = *(const bfrag8*)&xgB[(t*16+lo)*136 + kt*32 + q*8];
        acc[t] = __builtin_amdgcn_mfma_f32_16x16x32_bf16(a,b,acc[t],0,0,0);
      }
    }
    float bb = fb2[c];
#pragma unroll
    for (int t=0;t<2;t++)
#pragma unroll
      for (int r=0;r<4;r++){
        int i = t*16 + q*4 + r;
        if (i<25)
          out[(size_t)n*1600 + i*64 + c] = xF[i*68+c] + acc[t][r] + (i==0 ? bb : 0.f);
      }
  }
}

extern "C" void kernel_launch(void* const* d_in, const int* in_sizes, int n_in,
                              void* d_out, int out_size, void* d_ws, size_t ws_size,
                              hipStream_t stream) {
  (void)in_sizes; (void)n_in; (void)ws_size;
  const float* x     = (const float*)d_in[0];
  const int*   ei    = (const int*)d_in[1];
  const int*   an    = (const int*)d_in[2];
  const float* edist = (const float*)d_in[3];
  const float* wig   = (const float*)d_in[4];
  const float* stab  = (const float*)d_in[5];
  const float* ttab  = (const float*)d_in[6];
  const float* rw1   = (const float*)d_in[7];
  const float* rb1   = (const float*)d_in[8];
  const float* rw2   = (const float*)d_in[9];
  const float* rb2   = (const float*)d_in[10];
  const float* rw3   = (const float*)d_in[11];
  const float* rb3   = (const float*)d_in[12];
  const float* W1    = (const float*)d_in[13];
  const float* w0e   = (const float*)d_in[14];
  const float* adot  = (const float*)d_in[15];
  const float* tog   = (const float*)d_in[16];
  const float* fromg = (const float*)d_in[17];
  const float* proj  = (const float*)d_in[18];
  const float* g1    = (const float*)d_in[19];
  const float* g2    = (const float*)d_in[20];
  const float* glw   = (const float*)d_in[21];
  const float* glb   = (const float*)d_in[22];
  const float* fw1   = (const float*)d_in[23];
  const float* fb1   = (const float*)d_in[24];
  const float* fw2   = (const float*)d_in[25];
  const float* fb2   = (const float*)d_in[26];
  float* out = (float*)d_out;

  char* wsb = (char*)d_ws;
  short* hT    = (short*)(wsb);                    // N*64*32 bf16 = 40,960,000 B
  short* rfS   = (short*)(wsb + 40960000);         // E*640 bf16 = 64,000,000 B
  float* asum  = (float*)(wsb + 104960000);        // N*8 f32 = 320,000 B
  short* w1t   = (short*)(wsb + 105280000);        // 64*136*2 = 17408
  short* togA  = (short*)(wsb + 105297408);        // 48*40*2 = 3840
  short* fgA   = (short*)(wsb + 105301248);        // 32*72*2 = 4608
  short* projT = (short*)(wsb + 105305856);        // 64*64*2 = 8192
  short* fw1T  = (short*)(wsb + 105314048);        // 128*64*2 = 16384
  short* fw2T  = (short*)(wsb + 105330432);        // 64*128*2 = 16384
  short* rw1T  = (short*)(wsb + 105346816);        // 64*96*2 = 12288
  short* rw2T  = (short*)(wsb + 105359104);        // 64*64*2 = 8192
  short* rw3T  = (short*)(wsb + 105367296);        // 640*64*2 = 81920
  float* w0eN  = (float*)(wsb + 105449216);        // 192*128*4 = 98304

  hipMemsetAsync(asum, 0, (size_t)NN*8*sizeof(float), stream);
  hipMemsetAsync(d_out, 0, (size_t)out_size*sizeof(float), stream);  // d_out = agg

  k_wprep<<<32, 256, 0, stream>>>(W1, tog, fromg, proj, fw1, fw2, rw1, rw2, rw3, w0e,
                                  w1t, togA, fgA, projT, fw1T, fw2T,
                                  rw1T, rw2T, rw3T, w0eN);
  k_rms1T <<<(NN*64+255)/256, 256, 0, stream>>>(x, g1, hT);
  k_radial<<<(NE+31)/32, 256, 0, stream>>>(ei, an, edist, stab, ttab,
                                           rw1T, rb1, rw2T, rb2, rw3T, rb3, rfS);
  k_edge  <<<NE, 256, 0, stream>>>(hT, ei, wig, w1t, togA, fgA, w0eN, adot,
                                   rfS, asum, out);
  k_node  <<<NN, 256, 0, stream>>>(x, out, asum, projT, g2, glw, glb,
                                   fw1T, fb1, fw2T, fb2, togA, fgA, out);
}